// Round 17
// baseline (114.976 us; speedup 1.0000x reference)
//
#include <hip/hip_runtime.h>
#include <hip/hip_bf16.h>

// AgreementRouting, 4-kernel full-machine plan. R15 base (k-major u16 layout,
// PROVEN coalesced: for fixed k, lane l reads/writes consecutive dwords) +
// 4-deep prefetch + F merged into I3.
// B=128, IC=1152, OC=10, D=16, 3 iters, f32 in/out.
//
// R16 lesson: l-major "vectorized" layout (20B/lane chunks) broke coalescing
// (20B-strided unaligned vectors, ~20 cache lines/wave vs 4) -> +35us. The
// original [16k+l] addressing is already ideal; NEVER trade transaction
// pattern for instruction count.
//
// A  (1024x256): zero s_red[1..3]+cnt; stream f32 u ONCE (NT) -> u16 + s0
//     partials.
// I<T>(1024x256): prologue T==1: v=squash(reduce8 s0); T>1: v=v_acc[T-1]+
//     squash(s_red[T-1]) (thin, R15-proven). part0 stores v_acc[T]. 4-deep
//     prefetched 9-slice loop (first 4 loads issued BEFORE prologue).
//     atomicAdd row into s_red[T]. I3: last-arriving block per b (cnt[b]
//     ACQ_REL, R16-proven-correct) squashes s_red[3] -> out.
// Logits: bb_T = b_in + <u, sum_{t<T} v_t> (linearity, R2-proven).
//
// Lessons enforced: no in-kernel cross-block barrier/polling (R12: ~200us);
// no register-resident u (R11: spill); PARTS_=8 (R14: 18-way regressed).
//
// Lane scheme per 16-lane group (slice = 10x16 f32): l=tid&15, h=l>>3.
// Lane owns (j=2k+h, d=2(l&7)..2(l&7)+1), k=0..4 == float offset 32k+2l.
// Cross-lane in hot loops: all DPP (VALU pipe), R6-proven.

#define B_     128
#define IC_    1152
#define OC_    10
#define ROW_   160
#define WPS_   80      // bf16 dwords per slice
#define PARTS_ 8
#define SPB_   144     // slices per part
#define UPB_   9       // slices per 16-lane group
#define SOUT_  20480   // B_*ROW_

typedef float v2f __attribute__((ext_vector_type(2)));

__device__ __forceinline__ float bf_lo(uint32_t w) { return __uint_as_float(w << 16); }
__device__ __forceinline__ float bf_hi(uint32_t w) { return __uint_as_float(w & 0xffff0000u); }

template<int CTRL>
__device__ __forceinline__ float dppf(float x) {
    return __int_as_float(__builtin_amdgcn_update_dpp(
        0, __float_as_int(x), CTRL, 0xF, 0xF, true));
}
__device__ __forceinline__ float dpp_sum8(float x) {
    x += dppf<0xB1>(x);    // quad_perm [1,0,3,2]  (xor1)
    x += dppf<0x4E>(x);    // quad_perm [2,3,0,1]  (xor2)
    x += dppf<0x141>(x);   // row_half_mirror      (cross-quad within 8)
    return x;
}
__device__ __forceinline__ float softmax10(float own[5]) {
    float m = own[0];
#pragma unroll
    for (int k = 1; k < 5; ++k) m = fmaxf(m, own[k]);
    m = fmaxf(m, dppf<0x128>(m));          // row_ror:8 == xor8 within 16
    float sum = 0.f;
#pragma unroll
    for (int k = 0; k < 5; ++k) { own[k] = __expf(own[k] - m); sum += own[k]; }
    sum += dppf<0x128>(sum);
    return 1.f / sum;
}
__device__ __forceinline__ float squash_row(float x) {
    float sq = x * x;
    sq += __shfl_xor(sq, 1, 16);
    sq += __shfl_xor(sq, 2, 16);
    sq += __shfl_xor(sq, 4, 16);
    sq += __shfl_xor(sq, 8, 16);
    return (sq / (1.f + sq)) * x * rsqrtf(sq + 1e-8f);
}
__device__ __forceinline__ float agent_loadf(const float* p) {
    return __hip_atomic_load(p, __ATOMIC_RELAXED, __HIP_MEMORY_SCOPE_AGENT);
}

// ---------------- Kernel A ----------------
__global__ __launch_bounds__(256) void a_kernel(
    const float* __restrict__ u, const float* __restrict__ b_in,
    uint32_t* __restrict__ u16, float* __restrict__ s0_part,
    float* __restrict__ s_red)   // s_red[1..3] + cnt[B_], zeroed here
{
    const int bid = blockIdx.x, tid = threadIdx.x;
    const int l = tid & 15, h = l >> 3, g = tid >> 4;
    const int b = bid >> 3, part = bid & 7;
    const int wave = tid >> 6, lane = tid & 63;

    const int gidx = bid * 256 + tid;
    if (gidx < 3 * SOUT_ + B_) s_red[gidx] = 0.f;   // includes cnt as 0-bits

    __shared__ float red[4][ROW_];
    __shared__ float b_lds[SPB_ * OC_];

#pragma unroll
    for (int it = 0; it < 6; ++it) {
        int idx = it * 256 + tid;
        if (idx < SPB_ * OC_) b_lds[idx] = b_in[part * SPB_ * OC_ + idx];
    }
    __syncthreads();

    float2 sc[5];
#pragma unroll
    for (int k = 0; k < 5; ++k) { sc[k].x = 0.f; sc[k].y = 0.f; }
#pragma unroll
    for (int uu = 0; uu < UPB_; ++uu) {
        const int su = uu * 16 + g;
        const int i  = part * SPB_ + su;
        const v2f* up = (const v2f*)(u + (size_t)(b * IC_ + i) * ROW_ + 2 * l);
        v2f uv[5];
#pragma unroll
        for (int k = 0; k < 5; ++k) uv[k] = __builtin_nontemporal_load(up + 16 * k);

        uint32_t* wp = u16 + (size_t)(b * IC_ + i) * WPS_;
#pragma unroll
        for (int k = 0; k < 5; ++k) {
            __hip_bfloat16 bx = __float2bfloat16(uv[k].x);
            __hip_bfloat16 by = __float2bfloat16(uv[k].y);
            wp[16 * k + l] = ((uint32_t)(*(const uint16_t*)&by) << 16) |
                              (uint32_t)(*(const uint16_t*)&bx);
        }
        float own[5];
#pragma unroll
        for (int k = 0; k < 5; ++k) own[k] = b_lds[su * OC_ + 2 * k + h];
        const float inv = softmax10(own);
#pragma unroll
        for (int k = 0; k < 5; ++k) {
            float c = own[k] * inv;
            sc[k].x += c * uv[k].x; sc[k].y += c * uv[k].y;
        }
    }
#pragma unroll
    for (int k = 0; k < 5; ++k) {
        sc[k].x += __shfl_xor(sc[k].x, 16); sc[k].y += __shfl_xor(sc[k].y, 16);
        sc[k].x += __shfl_xor(sc[k].x, 32); sc[k].y += __shfl_xor(sc[k].y, 32);
    }
    if (lane < 16) {
#pragma unroll
        for (int k = 0; k < 5; ++k)
            *(float2*)&red[wave][32 * k + 2 * l] = sc[k];
    }
    __syncthreads();
    if (tid < ROW_) {
        float t = red[0][tid] + red[1][tid] + red[2][tid] + red[3][tid];
        s0_part[(size_t)(b * PARTS_ + part) * ROW_ + tid] = t;
    }
}

// ---------------- Kernel I<T> ----------------
template<int T>
__global__ __launch_bounds__(256) void i_kernel(
    const uint32_t* __restrict__ u16, const float* __restrict__ b_in,
    const float* __restrict__ s0_part, const float* __restrict__ s_red_prev,
    const float* __restrict__ v_in, float* __restrict__ v_out,
    float* __restrict__ s_out, uint32_t* __restrict__ cnt,
    float* __restrict__ out)
{
    const int bid = blockIdx.x, tid = threadIdx.x;
    const int l = tid & 15, h = l >> 3, g = tid >> 4;
    const int b = bid >> 3, part = bid & 7;
    const int wave = tid >> 6, lane = tid & 63;

    __shared__ float red[4][ROW_];
    __shared__ float v_lds[ROW_];
    __shared__ float b_lds[SPB_ * OC_];

#define B_LOAD(UW, uu) do {                                                 \
        const int su_ = (uu) * 16 + g;                                      \
        const uint32_t* wp_ = u16 + (size_t)(b * IC_ + part * SPB_ + su_) * WPS_; \
        _Pragma("unroll")                                                   \
        for (int k = 0; k < 5; ++k) UW[k] = wp_[16 * k + l];                \
    } while (0)

    // 4-deep prefetch, first 4 issued BEFORE the prologue (latency hidden
    // under the prologue's global reads; __syncthreads drains vmcnt)
    uint32_t uwA[5], uwB[5], uwC[5], uwD[5];
    B_LOAD(uwA, 0);
    B_LOAD(uwB, 1);
    B_LOAD(uwC, 2);
    B_LOAD(uwD, 3);

#pragma unroll
    for (int it = 0; it < 6; ++it) {
        int idx = it * 256 + tid;
        if (idx < SPB_ * OC_) b_lds[idx] = b_in[part * SPB_ * OC_ + idx];
    }

    if (tid < ROW_) {
        float vsum;
        if (T == 1) {
            const float* sp = s0_part + (size_t)(b * PARTS_) * ROW_;
            float x = 0.f;
#pragma unroll
            for (int p = 0; p < PARTS_; ++p) x += sp[p * ROW_ + tid];
            vsum = squash_row(x);
        } else {
            vsum = v_in[b * ROW_ + tid] + squash_row(s_red_prev[b * ROW_ + tid]);
        }
        if (T < 3 && part == 0) v_out[b * ROW_ + tid] = vsum;
        v_lds[tid] = vsum;
    }
    __syncthreads();

    float2 vv[5];
#pragma unroll
    for (int k = 0; k < 5; ++k)
        vv[k] = *(const float2*)&v_lds[32 * k + 2 * l];

    float2 sc[5];
#pragma unroll
    for (int k = 0; k < 5; ++k) { sc[k].x = 0.f; sc[k].y = 0.f; }

#define B_COMP(UW, uu) do {                                                 \
        const int su_ = (uu) * 16 + g;                                      \
        float own[5];                                                       \
        _Pragma("unroll")                                                   \
        for (int k = 0; k < 5; ++k) own[k] = b_lds[su_ * OC_ + 2 * k + h];  \
        _Pragma("unroll")                                                   \
        for (int k = 0; k < 5; ++k) {                                       \
            float pd = bf_lo(UW[k]) * vv[k].x + bf_hi(UW[k]) * vv[k].y;     \
            own[k] += dpp_sum8(pd);                                         \
        }                                                                   \
        const float inv = softmax10(own);                                   \
        _Pragma("unroll")                                                   \
        for (int k = 0; k < 5; ++k) {                                       \
            float c = own[k] * inv;                                         \
            sc[k].x += c * bf_lo(UW[k]); sc[k].y += c * bf_hi(UW[k]);       \
        }                                                                   \
    } while (0)

    B_COMP(uwA, 0); B_LOAD(uwA, 4);
    B_COMP(uwB, 1); B_LOAD(uwB, 5);
    B_COMP(uwC, 2); B_LOAD(uwC, 6);
    B_COMP(uwD, 3); B_LOAD(uwD, 7);
    B_COMP(uwA, 4); B_LOAD(uwA, 8);
    B_COMP(uwB, 5);
    B_COMP(uwC, 6);
    B_COMP(uwD, 7);
    B_COMP(uwA, 8);
#undef B_LOAD
#undef B_COMP

#pragma unroll
    for (int k = 0; k < 5; ++k) {
        sc[k].x += __shfl_xor(sc[k].x, 16); sc[k].y += __shfl_xor(sc[k].y, 16);
        sc[k].x += __shfl_xor(sc[k].x, 32); sc[k].y += __shfl_xor(sc[k].y, 32);
    }
    if (lane < 16) {
#pragma unroll
        for (int k = 0; k < 5; ++k)
            *(float2*)&red[wave][32 * k + 2 * l] = sc[k];
    }
    __syncthreads();
    if (tid < ROW_) {
        float t = red[0][tid] + red[1][tid] + red[2][tid] + red[3][tid];
        atomicAdd(&s_out[b * ROW_ + tid], t);
    }

    if (T == 3) {
        // last-arriving block of this b squashes the completed row -> out
        __shared__ int is_last;
        __syncthreads();           // drains this block's atomicAdds
        if (tid == 0) {
            __threadfence();
            uint32_t old = __hip_atomic_fetch_add(&cnt[b], 1u,
                              __ATOMIC_ACQ_REL, __HIP_MEMORY_SCOPE_AGENT);
            is_last = (old == PARTS_ - 1);
        }
        __syncthreads();
        if (is_last && tid < ROW_) {
            float x = agent_loadf(&s_out[b * ROW_ + tid]);
            out[b * ROW_ + tid] = squash_row(x);
        }
    }
}

extern "C" void kernel_launch(void* const* d_in, const int* in_sizes, int n_in,
                              void* d_out, int out_size, void* d_ws, size_t ws_size,
                              hipStream_t stream) {
    const float* u    = (const float*)d_in[0];
    const float* b_in = (const float*)d_in[1];
    float* out = (float*)d_out;

    float*    s0_part = (float*)d_ws;                          // B_*8*160 f32
    float*    s_red   = s0_part + (size_t)B_ * PARTS_ * ROW_;  // 3*SOUT_
    uint32_t* cnt     = (uint32_t*)(s_red + 3 * SOUT_);        // B_ u32
    float*    v_acc   = (float*)(cnt + B_);                    // 2*SOUT_
    uint32_t* u16     = (uint32_t*)(v_acc + 2 * SOUT_);        // 47.2 MB

    const dim3 blk(256);
    const dim3 grid(B_ * PARTS_);      // 1024

    a_kernel<<<grid, blk, 0, stream>>>(u, b_in, u16, s0_part, s_red);
    i_kernel<1><<<grid, blk, 0, stream>>>(u16, b_in, s0_part, nullptr,
                                          nullptr, v_acc, s_red,
                                          nullptr, nullptr);
    i_kernel<2><<<grid, blk, 0, stream>>>(u16, b_in, s0_part, s_red,
                                          v_acc, v_acc + SOUT_, s_red + SOUT_,
                                          nullptr, nullptr);
    i_kernel<3><<<grid, blk, 0, stream>>>(u16, b_in, s0_part, s_red + SOUT_,
                                          v_acc + SOUT_, nullptr, s_red + 2 * SOUT_,
                                          cnt, out);
}

// Round 18
// 70.031 us; speedup vs baseline: 1.6418x; 1.6418x over previous
//
#include <hip/hip_runtime.h>
#include <hip/hip_bf16.h>

// AgreementRouting, 5-kernel full-machine plan = EXACT R15 (68.9us best) +
// ONE change: 4-deep prefetch in I kernels. B=128, IC=1152, OC=10, D=16.
//
// R16/R17 post-mortem: the +35..46us regressions track the F-merge tail's
// per-block __threadfence + ACQ_REL agent atomic (L2 writeback/invalidate
// maintenance, ~0.3-0.5us x 1024 blocks) -- NOT the u16 layout. Law: no
// agent-scope fences/ordered atomics anywhere; relaxed atomicAdd only.
//
// A  (1024x256): zero s_red[1..3]; stream f32 u ONCE (NT) -> u16 (k-major,
//     coalesced) + s0 partials.
// I<T>(1024x256): prologue T==1: v=squash(reduce8 s0); T>1: v=v_acc[T-1]+
//     squash(s_red[T-1]). part0 stores v_acc[T]. 4-deep prefetched 9-slice
//     loop (first 4 loads issued BEFORE prologue; the prologue-ending
//     __syncthreads drains vmcnt). Relaxed atomicAdd row into s_red[T].
// F  (80x256): out = squash(s_red[3]). Separate kernel: fence-free.
// Logits: bb_T = b_in + <u, sum_{t<T} v_t> (linearity, R2-proven).
//
// Lessons enforced: kernel-boundary sync only (R12); no register-resident u
// (R11 spill); PARTS_=8 (R14); k-major u16 (R16); no fences (R17).
//
// Lane scheme per 16-lane group (slice = 10x16 f32): l=tid&15, h=l>>3.
// Lane owns (j=2k+h, d=2(l&7)..2(l&7)+1), k=0..4 == float offset 32k+2l.
// Cross-lane in hot loops: all DPP (VALU pipe), R6-proven.

#define B_     128
#define IC_    1152
#define OC_    10
#define ROW_   160
#define WPS_   80      // bf16 dwords per slice
#define PARTS_ 8
#define SPB_   144     // slices per part
#define UPB_   9       // slices per 16-lane group
#define SOUT_  20480   // B_*ROW_

typedef float v2f __attribute__((ext_vector_type(2)));

__device__ __forceinline__ float bf_lo(uint32_t w) { return __uint_as_float(w << 16); }
__device__ __forceinline__ float bf_hi(uint32_t w) { return __uint_as_float(w & 0xffff0000u); }

template<int CTRL>
__device__ __forceinline__ float dppf(float x) {
    return __int_as_float(__builtin_amdgcn_update_dpp(
        0, __float_as_int(x), CTRL, 0xF, 0xF, true));
}
__device__ __forceinline__ float dpp_sum8(float x) {
    x += dppf<0xB1>(x);    // quad_perm [1,0,3,2]  (xor1)
    x += dppf<0x4E>(x);    // quad_perm [2,3,0,1]  (xor2)
    x += dppf<0x141>(x);   // row_half_mirror      (cross-quad within 8)
    return x;
}
__device__ __forceinline__ float softmax10(float own[5]) {
    float m = own[0];
#pragma unroll
    for (int k = 1; k < 5; ++k) m = fmaxf(m, own[k]);
    m = fmaxf(m, dppf<0x128>(m));          // row_ror:8 == xor8 within 16
    float sum = 0.f;
#pragma unroll
    for (int k = 0; k < 5; ++k) { own[k] = __expf(own[k] - m); sum += own[k]; }
    sum += dppf<0x128>(sum);
    return 1.f / sum;
}
__device__ __forceinline__ float squash_row(float x) {
    float sq = x * x;
    sq += __shfl_xor(sq, 1, 16);
    sq += __shfl_xor(sq, 2, 16);
    sq += __shfl_xor(sq, 4, 16);
    sq += __shfl_xor(sq, 8, 16);
    return (sq / (1.f + sq)) * x * rsqrtf(sq + 1e-8f);
}

// ---------------- Kernel A ----------------
__global__ __launch_bounds__(256) void a_kernel(
    const float* __restrict__ u, const float* __restrict__ b_in,
    uint32_t* __restrict__ u16, float* __restrict__ s0_part,
    float* __restrict__ s_red)   // s_red[1..3], zeroed here
{
    const int bid = blockIdx.x, tid = threadIdx.x;
    const int l = tid & 15, h = l >> 3, g = tid >> 4;
    const int b = bid >> 3, part = bid & 7;
    const int wave = tid >> 6, lane = tid & 63;

    const int gidx = bid * 256 + tid;
    if (gidx < 3 * SOUT_) s_red[gidx] = 0.f;

    __shared__ float red[4][ROW_];
    __shared__ float b_lds[SPB_ * OC_];

#pragma unroll
    for (int it = 0; it < 6; ++it) {
        int idx = it * 256 + tid;
        if (idx < SPB_ * OC_) b_lds[idx] = b_in[part * SPB_ * OC_ + idx];
    }
    __syncthreads();

    float2 sc[5];
#pragma unroll
    for (int k = 0; k < 5; ++k) { sc[k].x = 0.f; sc[k].y = 0.f; }
#pragma unroll
    for (int uu = 0; uu < UPB_; ++uu) {
        const int su = uu * 16 + g;
        const int i  = part * SPB_ + su;
        const v2f* up = (const v2f*)(u + (size_t)(b * IC_ + i) * ROW_ + 2 * l);
        v2f uv[5];
#pragma unroll
        for (int k = 0; k < 5; ++k) uv[k] = __builtin_nontemporal_load(up + 16 * k);

        uint32_t* wp = u16 + (size_t)(b * IC_ + i) * WPS_;
#pragma unroll
        for (int k = 0; k < 5; ++k) {
            __hip_bfloat16 bx = __float2bfloat16(uv[k].x);
            __hip_bfloat16 by = __float2bfloat16(uv[k].y);
            wp[16 * k + l] = ((uint32_t)(*(const uint16_t*)&by) << 16) |
                              (uint32_t)(*(const uint16_t*)&bx);
        }
        float own[5];
#pragma unroll
        for (int k = 0; k < 5; ++k) own[k] = b_lds[su * OC_ + 2 * k + h];
        const float inv = softmax10(own);
#pragma unroll
        for (int k = 0; k < 5; ++k) {
            float c = own[k] * inv;
            sc[k].x += c * uv[k].x; sc[k].y += c * uv[k].y;
        }
    }
#pragma unroll
    for (int k = 0; k < 5; ++k) {
        sc[k].x += __shfl_xor(sc[k].x, 16); sc[k].y += __shfl_xor(sc[k].y, 16);
        sc[k].x += __shfl_xor(sc[k].x, 32); sc[k].y += __shfl_xor(sc[k].y, 32);
    }
    if (lane < 16) {
#pragma unroll
        for (int k = 0; k < 5; ++k)
            *(float2*)&red[wave][32 * k + 2 * l] = sc[k];
    }
    __syncthreads();
    if (tid < ROW_) {
        float t = red[0][tid] + red[1][tid] + red[2][tid] + red[3][tid];
        s0_part[(size_t)(b * PARTS_ + part) * ROW_ + tid] = t;
    }
}

// ---------------- Kernel I<T> ----------------
template<int T>
__global__ __launch_bounds__(256) void i_kernel(
    const uint32_t* __restrict__ u16, const float* __restrict__ b_in,
    const float* __restrict__ s0_part, const float* __restrict__ s_red_prev,
    const float* __restrict__ v_in, float* __restrict__ v_out,
    float* __restrict__ s_out)
{
    const int bid = blockIdx.x, tid = threadIdx.x;
    const int l = tid & 15, h = l >> 3, g = tid >> 4;
    const int b = bid >> 3, part = bid & 7;
    const int wave = tid >> 6, lane = tid & 63;

    __shared__ float red[4][ROW_];
    __shared__ float v_lds[ROW_];
    __shared__ float b_lds[SPB_ * OC_];

#define B_LOAD(UW, uu) do {                                                 \
        const int su_ = (uu) * 16 + g;                                      \
        const uint32_t* wp_ = u16 + (size_t)(b * IC_ + part * SPB_ + su_) * WPS_; \
        _Pragma("unroll")                                                   \
        for (int k = 0; k < 5; ++k) UW[k] = wp_[16 * k + l];                \
    } while (0)

    // 4-deep prefetch, first 4 issued BEFORE the prologue
    uint32_t uwA[5], uwB[5], uwC[5], uwD[5];
    B_LOAD(uwA, 0);
    B_LOAD(uwB, 1);
    B_LOAD(uwC, 2);
    B_LOAD(uwD, 3);

#pragma unroll
    for (int it = 0; it < 6; ++it) {
        int idx = it * 256 + tid;
        if (idx < SPB_ * OC_) b_lds[idx] = b_in[part * SPB_ * OC_ + idx];
    }

    if (tid < ROW_) {
        float vsum;
        if (T == 1) {
            const float* sp = s0_part + (size_t)(b * PARTS_) * ROW_;
            float x = 0.f;
#pragma unroll
            for (int p = 0; p < PARTS_; ++p) x += sp[p * ROW_ + tid];
            vsum = squash_row(x);
        } else {
            vsum = v_in[b * ROW_ + tid] + squash_row(s_red_prev[b * ROW_ + tid]);
        }
        if (T < 3 && part == 0) v_out[b * ROW_ + tid] = vsum;
        v_lds[tid] = vsum;
    }
    __syncthreads();

    float2 vv[5];
#pragma unroll
    for (int k = 0; k < 5; ++k)
        vv[k] = *(const float2*)&v_lds[32 * k + 2 * l];

    float2 sc[5];
#pragma unroll
    for (int k = 0; k < 5; ++k) { sc[k].x = 0.f; sc[k].y = 0.f; }

#define B_COMP(UW, uu) do {                                                 \
        const int su_ = (uu) * 16 + g;                                      \
        float own[5];                                                       \
        _Pragma("unroll")                                                   \
        for (int k = 0; k < 5; ++k) own[k] = b_lds[su_ * OC_ + 2 * k + h];  \
        _Pragma("unroll")                                                   \
        for (int k = 0; k < 5; ++k) {                                       \
            float pd = bf_lo(UW[k]) * vv[k].x + bf_hi(UW[k]) * vv[k].y;     \
            own[k] += dpp_sum8(pd);                                         \
        }                                                                   \
        const float inv = softmax10(own);                                   \
        _Pragma("unroll")                                                   \
        for (int k = 0; k < 5; ++k) {                                       \
            float c = own[k] * inv;                                         \
            sc[k].x += c * bf_lo(UW[k]); sc[k].y += c * bf_hi(UW[k]);       \
        }                                                                   \
    } while (0)

    B_COMP(uwA, 0); B_LOAD(uwA, 4);
    B_COMP(uwB, 1); B_LOAD(uwB, 5);
    B_COMP(uwC, 2); B_LOAD(uwC, 6);
    B_COMP(uwD, 3); B_LOAD(uwD, 7);
    B_COMP(uwA, 4); B_LOAD(uwA, 8);
    B_COMP(uwB, 5);
    B_COMP(uwC, 6);
    B_COMP(uwD, 7);
    B_COMP(uwA, 8);
#undef B_LOAD
#undef B_COMP

#pragma unroll
    for (int k = 0; k < 5; ++k) {
        sc[k].x += __shfl_xor(sc[k].x, 16); sc[k].y += __shfl_xor(sc[k].y, 16);
        sc[k].x += __shfl_xor(sc[k].x, 32); sc[k].y += __shfl_xor(sc[k].y, 32);
    }
    if (lane < 16) {
#pragma unroll
        for (int k = 0; k < 5; ++k)
            *(float2*)&red[wave][32 * k + 2 * l] = sc[k];
    }
    __syncthreads();
    if (tid < ROW_) {
        float t = red[0][tid] + red[1][tid] + red[2][tid] + red[3][tid];
        atomicAdd(&s_out[b * ROW_ + tid], t);   // relaxed device atomic: no fences
    }
}

// ---------------- Kernel F ----------------
__global__ __launch_bounds__(256) void f_kernel(
    const float* __restrict__ s3, float* __restrict__ out)
{
    const int idx = blockIdx.x * 256 + threadIdx.x;   // 0..SOUT_-1
    out[idx] = squash_row(s3[idx]);
}

extern "C" void kernel_launch(void* const* d_in, const int* in_sizes, int n_in,
                              void* d_out, int out_size, void* d_ws, size_t ws_size,
                              hipStream_t stream) {
    const float* u    = (const float*)d_in[0];
    const float* b_in = (const float*)d_in[1];
    float* out = (float*)d_out;

    float*    s0_part = (float*)d_ws;                          // B_*8*160 f32
    float*    s_red   = s0_part + (size_t)B_ * PARTS_ * ROW_;  // 3*SOUT_
    float*    v_acc   = s_red + 3 * SOUT_;                     // 2*SOUT_
    uint32_t* u16     = (uint32_t*)(v_acc + 2 * SOUT_);        // 47.2 MB

    const dim3 blk(256);
    const dim3 grid(B_ * PARTS_);      // 1024

    a_kernel<<<grid, blk, 0, stream>>>(u, b_in, u16, s0_part, s_red);
    i_kernel<1><<<grid, blk, 0, stream>>>(u16, b_in, s0_part, nullptr,
                                          nullptr, v_acc, s_red);
    i_kernel<2><<<grid, blk, 0, stream>>>(u16, b_in, s0_part, s_red,
                                          v_acc, v_acc + SOUT_, s_red + SOUT_);
    i_kernel<3><<<grid, blk, 0, stream>>>(u16, b_in, s0_part, s_red + SOUT_,
                                          v_acc + SOUT_, nullptr, s_red + 2 * SOUT_);
    f_kernel<<<dim3(SOUT_ / 256), blk, 0, stream>>>(s_red + 2 * SOUT_, out);
}

// Round 19
// 68.497 us; speedup vs baseline: 1.6785x; 1.0224x over previous
//
#include <hip/hip_runtime.h>
#include <hip/hip_bf16.h>

// AgreementRouting, 5-kernel full-machine plan = R15 (68.9us best) with the
// I-kernel partition widened 8 -> 12 (decoupled from A's 8-way partition).
// B=128, IC=1152, OC=10, D=16, 3 iters, f32 in/out.
//
// Rationale: R18 proved the I slice-loop is NOT per-wave latency-bound
// (4-deep prefetch neutral). At 1024 blocks the I kernels run 16 waves/CU
// (50% occ). The R15 v_acc chain made prologue cost partition-independent
// (T>1 reads 1-2 rows; T=1 reads the fixed 8 A-partials), so finer I
// partitioning is now free: PARTS_I=12 -> 1536 blocks, 24 waves/CU (75%).
//
// A  (1024x256, PARTS_A=8): zero s_red[1..3]; stream f32 u ONCE (NT) ->
//     u16 (k-major, coalesced) + s0 partials. Unchanged from R15.
// I<T>(1536x256, PARTS_I=12): prologue T==1: v=squash(reduce8 s0); T>1:
//     v=v_acc[T-1]+squash(s_red[T-1]). part0 stores v_acc[T]. 2-deep
//     prefetched 6-slice loop (first 2 loads before prologue). Relaxed
//     atomicAdd row into s_red[T] (12-way/elem; R1 proved 72-way fine).
// F  (80x256): out = squash(s_red[3]).
// Logits: bb_T = b_in + <u, sum_{t<T} v_t> (linearity, R2-proven).
//
// Laws enforced: kernel-boundary sync only (R12); no agent fences/ordered
// atomics (R17: ~35us); no register-resident u (R11); k-major u16 (R16).
//
// Lane scheme per 16-lane group (slice = 10x16 f32): l=tid&15, h=l>>3.
// Lane owns (j=2k+h, d=2(l&7)..2(l&7)+1), k=0..4 == float offset 32k+2l.
// Cross-lane in hot loops: all DPP (VALU pipe), R6-proven.

#define B_      128
#define IC_     1152
#define OC_     10
#define ROW_    160
#define WPS_    80      // bf16 dwords per slice
#define PARTS_A 8
#define SPB_A   144     // slices per A-part
#define UPB_A   9       // slices per 16-lane group in A
#define PARTS_I 12
#define SPB_I   96      // slices per I-part
#define UPB_I   6       // slices per 16-lane group in I
#define SOUT_   20480   // B_*ROW_

typedef float v2f __attribute__((ext_vector_type(2)));

__device__ __forceinline__ float bf_lo(uint32_t w) { return __uint_as_float(w << 16); }
__device__ __forceinline__ float bf_hi(uint32_t w) { return __uint_as_float(w & 0xffff0000u); }

template<int CTRL>
__device__ __forceinline__ float dppf(float x) {
    return __int_as_float(__builtin_amdgcn_update_dpp(
        0, __float_as_int(x), CTRL, 0xF, 0xF, true));
}
__device__ __forceinline__ float dpp_sum8(float x) {
    x += dppf<0xB1>(x);    // quad_perm [1,0,3,2]  (xor1)
    x += dppf<0x4E>(x);    // quad_perm [2,3,0,1]  (xor2)
    x += dppf<0x141>(x);   // row_half_mirror      (cross-quad within 8)
    return x;
}
__device__ __forceinline__ float softmax10(float own[5]) {
    float m = own[0];
#pragma unroll
    for (int k = 1; k < 5; ++k) m = fmaxf(m, own[k]);
    m = fmaxf(m, dppf<0x128>(m));          // row_ror:8 == xor8 within 16
    float sum = 0.f;
#pragma unroll
    for (int k = 0; k < 5; ++k) { own[k] = __expf(own[k] - m); sum += own[k]; }
    sum += dppf<0x128>(sum);
    return 1.f / sum;
}
__device__ __forceinline__ float squash_row(float x) {
    float sq = x * x;
    sq += __shfl_xor(sq, 1, 16);
    sq += __shfl_xor(sq, 2, 16);
    sq += __shfl_xor(sq, 4, 16);
    sq += __shfl_xor(sq, 8, 16);
    return (sq / (1.f + sq)) * x * rsqrtf(sq + 1e-8f);
}

// ---------------- Kernel A (unchanged from R15) ----------------
__global__ __launch_bounds__(256) void a_kernel(
    const float* __restrict__ u, const float* __restrict__ b_in,
    uint32_t* __restrict__ u16, float* __restrict__ s0_part,
    float* __restrict__ s_red)   // s_red[1..3], zeroed here
{
    const int bid = blockIdx.x, tid = threadIdx.x;
    const int l = tid & 15, h = l >> 3, g = tid >> 4;
    const int b = bid >> 3, part = bid & 7;
    const int wave = tid >> 6, lane = tid & 63;

    const int gidx = bid * 256 + tid;
    if (gidx < 3 * SOUT_) s_red[gidx] = 0.f;

    __shared__ float red[4][ROW_];
    __shared__ float b_lds[SPB_A * OC_];

#pragma unroll
    for (int it = 0; it < 6; ++it) {
        int idx = it * 256 + tid;
        if (idx < SPB_A * OC_) b_lds[idx] = b_in[part * SPB_A * OC_ + idx];
    }
    __syncthreads();

    float2 sc[5];
#pragma unroll
    for (int k = 0; k < 5; ++k) { sc[k].x = 0.f; sc[k].y = 0.f; }
#pragma unroll
    for (int uu = 0; uu < UPB_A; ++uu) {
        const int su = uu * 16 + g;
        const int i  = part * SPB_A + su;
        const v2f* up = (const v2f*)(u + (size_t)(b * IC_ + i) * ROW_ + 2 * l);
        v2f uv[5];
#pragma unroll
        for (int k = 0; k < 5; ++k) uv[k] = __builtin_nontemporal_load(up + 16 * k);

        uint32_t* wp = u16 + (size_t)(b * IC_ + i) * WPS_;
#pragma unroll
        for (int k = 0; k < 5; ++k) {
            __hip_bfloat16 bx = __float2bfloat16(uv[k].x);
            __hip_bfloat16 by = __float2bfloat16(uv[k].y);
            wp[16 * k + l] = ((uint32_t)(*(const uint16_t*)&by) << 16) |
                              (uint32_t)(*(const uint16_t*)&bx);
        }
        float own[5];
#pragma unroll
        for (int k = 0; k < 5; ++k) own[k] = b_lds[su * OC_ + 2 * k + h];
        const float inv = softmax10(own);
#pragma unroll
        for (int k = 0; k < 5; ++k) {
            float c = own[k] * inv;
            sc[k].x += c * uv[k].x; sc[k].y += c * uv[k].y;
        }
    }
#pragma unroll
    for (int k = 0; k < 5; ++k) {
        sc[k].x += __shfl_xor(sc[k].x, 16); sc[k].y += __shfl_xor(sc[k].y, 16);
        sc[k].x += __shfl_xor(sc[k].x, 32); sc[k].y += __shfl_xor(sc[k].y, 32);
    }
    if (lane < 16) {
#pragma unroll
        for (int k = 0; k < 5; ++k)
            *(float2*)&red[wave][32 * k + 2 * l] = sc[k];
    }
    __syncthreads();
    if (tid < ROW_) {
        float t = red[0][tid] + red[1][tid] + red[2][tid] + red[3][tid];
        s0_part[(size_t)(b * PARTS_A + part) * ROW_ + tid] = t;
    }
}

// ---------------- Kernel I<T> (PARTS_I = 12) ----------------
template<int T>
__global__ __launch_bounds__(256) void i_kernel(
    const uint32_t* __restrict__ u16, const float* __restrict__ b_in,
    const float* __restrict__ s0_part, const float* __restrict__ s_red_prev,
    const float* __restrict__ v_in, float* __restrict__ v_out,
    float* __restrict__ s_out)
{
    const int bid = blockIdx.x, tid = threadIdx.x;
    const int l = tid & 15, h = l >> 3, g = tid >> 4;
    const int b = bid / PARTS_I, part = bid % PARTS_I;
    const int wave = tid >> 6, lane = tid & 63;

    __shared__ float red[4][ROW_];
    __shared__ float v_lds[ROW_];
    __shared__ float b_lds[SPB_I * OC_];   // 960 floats

#define B_LOAD(UW, uu) do {                                                 \
        const int su_ = (uu) * 16 + g;                                      \
        const uint32_t* wp_ = u16 + (size_t)(b * IC_ + part * SPB_I + su_) * WPS_; \
        _Pragma("unroll")                                                   \
        for (int k = 0; k < 5; ++k) UW[k] = wp_[16 * k + l];                \
    } while (0)

    // 2-deep prefetch (R15-proven), first 2 issued BEFORE the prologue
    uint32_t uwA[5], uwB[5];
    B_LOAD(uwA, 0);
    B_LOAD(uwB, 1);

#pragma unroll
    for (int it = 0; it < 4; ++it) {
        int idx = it * 256 + tid;
        if (idx < SPB_I * OC_) b_lds[idx] = b_in[part * SPB_I * OC_ + idx];
    }

    if (tid < ROW_) {
        float vsum;
        if (T == 1) {
            const float* sp = s0_part + (size_t)(b * PARTS_A) * ROW_;
            float x = 0.f;
#pragma unroll
            for (int p = 0; p < PARTS_A; ++p) x += sp[p * ROW_ + tid];
            vsum = squash_row(x);
        } else {
            vsum = v_in[b * ROW_ + tid] + squash_row(s_red_prev[b * ROW_ + tid]);
        }
        if (T < 3 && part == 0) v_out[b * ROW_ + tid] = vsum;
        v_lds[tid] = vsum;
    }
    __syncthreads();

    float2 vv[5];
#pragma unroll
    for (int k = 0; k < 5; ++k)
        vv[k] = *(const float2*)&v_lds[32 * k + 2 * l];

    float2 sc[5];
#pragma unroll
    for (int k = 0; k < 5; ++k) { sc[k].x = 0.f; sc[k].y = 0.f; }

#define B_COMP(UW, uu) do {                                                 \
        const int su_ = (uu) * 16 + g;                                      \
        float own[5];                                                       \
        _Pragma("unroll")                                                   \
        for (int k = 0; k < 5; ++k) own[k] = b_lds[su_ * OC_ + 2 * k + h];  \
        _Pragma("unroll")                                                   \
        for (int k = 0; k < 5; ++k) {                                       \
            float pd = bf_lo(UW[k]) * vv[k].x + bf_hi(UW[k]) * vv[k].y;     \
            own[k] += dpp_sum8(pd);                                         \
        }                                                                   \
        const float inv = softmax10(own);                                   \
        _Pragma("unroll")                                                   \
        for (int k = 0; k < 5; ++k) {                                       \
            float c = own[k] * inv;                                         \
            sc[k].x += c * bf_lo(UW[k]); sc[k].y += c * bf_hi(UW[k]);       \
        }                                                                   \
    } while (0)

    B_COMP(uwA, 0); B_LOAD(uwA, 2);
    B_COMP(uwB, 1); B_LOAD(uwB, 3);
    B_COMP(uwA, 2); B_LOAD(uwA, 4);
    B_COMP(uwB, 3); B_LOAD(uwB, 5);
    B_COMP(uwA, 4);
    B_COMP(uwB, 5);
#undef B_LOAD
#undef B_COMP

#pragma unroll
    for (int k = 0; k < 5; ++k) {
        sc[k].x += __shfl_xor(sc[k].x, 16); sc[k].y += __shfl_xor(sc[k].y, 16);
        sc[k].x += __shfl_xor(sc[k].x, 32); sc[k].y += __shfl_xor(sc[k].y, 32);
    }
    if (lane < 16) {
#pragma unroll
        for (int k = 0; k < 5; ++k)
            *(float2*)&red[wave][32 * k + 2 * l] = sc[k];
    }
    __syncthreads();
    if (tid < ROW_) {
        float t = red[0][tid] + red[1][tid] + red[2][tid] + red[3][tid];
        atomicAdd(&s_out[b * ROW_ + tid], t);   // relaxed device atomic: no fences
    }
}

// ---------------- Kernel F ----------------
__global__ __launch_bounds__(256) void f_kernel(
    const float* __restrict__ s3, float* __restrict__ out)
{
    const int idx = blockIdx.x * 256 + threadIdx.x;   // 0..SOUT_-1
    out[idx] = squash_row(s3[idx]);
}

extern "C" void kernel_launch(void* const* d_in, const int* in_sizes, int n_in,
                              void* d_out, int out_size, void* d_ws, size_t ws_size,
                              hipStream_t stream) {
    const float* u    = (const float*)d_in[0];
    const float* b_in = (const float*)d_in[1];
    float* out = (float*)d_out;

    float*    s0_part = (float*)d_ws;                           // B_*8*160 f32
    float*    s_red   = s0_part + (size_t)B_ * PARTS_A * ROW_;  // 3*SOUT_
    float*    v_acc   = s_red + 3 * SOUT_;                      // 2*SOUT_
    uint32_t* u16     = (uint32_t*)(v_acc + 2 * SOUT_);         // 47.2 MB

    const dim3 blk(256);

    a_kernel<<<dim3(B_ * PARTS_A), blk, 0, stream>>>(u, b_in, u16, s0_part, s_red);
    i_kernel<1><<<dim3(B_ * PARTS_I), blk, 0, stream>>>(u16, b_in, s0_part, nullptr,
                                          nullptr, v_acc, s_red);
    i_kernel<2><<<dim3(B_ * PARTS_I), blk, 0, stream>>>(u16, b_in, s0_part, s_red,
                                          v_acc, v_acc + SOUT_, s_red + SOUT_);
    i_kernel<3><<<dim3(B_ * PARTS_I), blk, 0, stream>>>(u16, b_in, s0_part, s_red + SOUT_,
                                          v_acc + SOUT_, nullptr, s_red + 2 * SOUT_);
    f_kernel<<<dim3(SOUT_ / 256), blk, 0, stream>>>(s_red + 2 * SOUT_, out);
}